// Round 8
// baseline (592.182 us; speedup 1.0000x reference)
//
#include <hip/hip_runtime.h>
#include <hip/hip_bf16.h>

// Mamba2 fused block, MI355X. Round 14: reads+MFMA same-side-of-barrier in
// both deep GEMMs (T3 minimum-recipe order: drain -> BAR -> STAGE -> ds_read
// -> MFMA) so the compiler can overlap LDS reads with MFMA via fine lgkmcnt.
// Round-13 structure had reads pre-barrier / MFMA post -> pipes serialized
// (phase ~1100cy vs 400cy floor, MfmaUtil 28%). Drains retimed to wait half h
// at iter h (vmcnt 8/4/0; gemm8o 6/3/0). k_conv vectorized bf16x8.

#define LL 4096
#define DPROJ 4384
#define CONVD 2304
#define DIN 2048
#define NH 32
#define HD 64
#define DS 128
#define CH 256
#define NC 16

typedef unsigned short u16;
typedef unsigned int u32;
typedef __attribute__((ext_vector_type(8))) short bf16x8;
typedef __attribute__((ext_vector_type(4))) float f32x4;

__device__ __forceinline__ float bf2f(u16 v) {
    u32 x = ((u32)v) << 16;
    float f; __builtin_memcpy(&f, &x, 4); return f;
}
__device__ __forceinline__ u16 f2bf(float f) {
    u32 x; __builtin_memcpy(&x, &f, 4);
    u32 r = (x + 0x7fffu + ((x >> 16) & 1u)) >> 16;   // RNE
    return (u16)r;
}
__device__ __forceinline__ float ldin(const void* p, size_t i, int bf) {
    if (bf) return bf2f(((const u16*)p)[i]);
    return ((const float*)p)[i];
}
__device__ __forceinline__ void stout(void* p, size_t i, int bf, float v) {
    if (bf) ((u16*)p)[i] = f2bf(v);
    else    ((float*)p)[i] = v;
}
__device__ __forceinline__ void gll16(const u16* g, u16* l) {
    __builtin_amdgcn_global_load_lds((const u32*)g, (u32*)l, 16, 0, 0);
}

// ---------------- dtype detector ----------------
__global__ void k_detect(const void* u, int* flag) {
    __shared__ int cnt;
    if (threadIdx.x == 0) cnt = 0;
    __syncthreads();
    u16 bits = ((const u16*)u)[2 * threadIdx.x];
    int e = (bits >> 7) & 0xff;
    int ok = (e >= 100 && e <= 141) ? 1 : 0;
    atomicAdd(&cnt, ok);
    __syncthreads();
    if (threadIdx.x == 0) *flag = (cnt > 128) ? 1 : 0;
}

// ---------------- cast to bf16 (identity when input already bf16) ----------------
__global__ void k_cast(const void* src, u16* dst, const int* flagp, int n4) {
    int fl = *flagp;
    size_t i = (size_t)blockIdx.x * 256 + threadIdx.x;
    if (i >= (size_t)n4) return;
    if (fl) {
        ((u32*)dst)[i * 2]     = ((const u32*)src)[i * 2];
        ((u32*)dst)[i * 2 + 1] = ((const u32*)src)[i * 2 + 1];
    } else {
        float4 v = ((const float4*)src)[i];
        dst[i * 4 + 0] = f2bf(v.x); dst[i * 4 + 1] = f2bf(v.y);
        dst[i * 4 + 2] = f2bf(v.z); dst[i * 4 + 3] = f2bf(v.w);
    }
}

// ---------------- transpose + cast: src[R][Cc] -> dst[Cpad][R] bf16, zero-fill ----------------
__global__ __launch_bounds__(256) void k_transpose(const void* src, u16* dst,
                                                   int R, int Cc, const int* flagp) {
    int fl = *flagp;
    __shared__ float tile[32][33];
    int r0 = blockIdx.y * 32, c0 = blockIdx.x * 32;
    int t = threadIdx.x;
    int tr = t >> 5, tc = t & 31;
#pragma unroll
    for (int i = 0; i < 4; ++i) {
        int r = r0 + tr + i * 8, c = c0 + tc;
        float v = 0.f;
        if (c < Cc) v = ldin(src, (size_t)r * Cc + c, fl);
        tile[tr + i * 8][tc] = v;
    }
    __syncthreads();
#pragma unroll
    for (int i = 0; i < 4; ++i) {
        int c = c0 + tr + i * 8, r = r0 + tc;
        dst[(size_t)c * R + r] = f2bf(tile[tc][tr + i * 8]);
    }
}

// ---------------- 256x256 deep-pipelined MFMA GEMM for the in-projection ----------------
// LDS: ring of 4 K-half slots per matrix (slot = h&3). A [0..32768) hw,
// B [32768..65536) hw. Super-row (2 rows) = 64 hw; slot16 = (q|(par<<2))^(sr&7).
// Loop order: drain(h) -> BAR -> STAGE(h+3) -> ds_read(h) -> MFMA(h).
__global__ __launch_bounds__(512) void k_gemm8(const u16* __restrict__ A, const u16* __restrict__ Bt,
                                               u16* o0, u16* o1, u16* o2) {
    constexpr int K = 1024;
    constexpr int NKH = K / 32;   // 32 K-halves
    __shared__ __align__(16) u16 lds[65536];   // 128 KiB

    int tid = threadIdx.x;
    int lane = tid & 63, w = tid >> 6;
    int wm = w >> 2, wn = w & 3;
    int q = lane >> 4, l15 = lane & 15;

    int flat = blockIdx.x;                 // 576 blocks, 576 % 8 == 0 -> bijective XCD swizzle
    int swz = (flat & 7) * 72 + (flat >> 3);
    int tm = swz / 18, tn = swz % 18;
    int m0 = tm * 256, n0 = tn * 256;

    size_t srcA[2], srcB[2];
    int ldsW[2];
#pragma unroll
    for (int r = 0; r < 2; ++r) {
        int slotIdx = r * 512 + tid;
        int sr = slotIdx >> 3, s = slotIdx & 7;
        int qp = s ^ (sr & 7);
        int rr = sr * 2 + (qp >> 2), kg = qp & 3;
        srcA[r] = (size_t)(m0 + rr) * K + kg * 8;
        srcB[r] = (size_t)(n0 + rr) * K + kg * 8;
        ldsW[r] = (r * 512 + (tid & ~63)) * 8;
    }

    int offA[8], offB[4];
#pragma unroll
    for (int i = 0; i < 8; ++i) {
        int rl = wm * 128 + i * 16 + l15;
        int sr = rl >> 1, qp = q | ((rl & 1) << 2);
        offA[i] = sr * 64 + (qp ^ (sr & 7)) * 8;
    }
#pragma unroll
    for (int j = 0; j < 4; ++j) {
        int nl = wn * 64 + j * 16 + l15;
        int sr = nl >> 1, qp = q | ((nl & 1) << 2);
        offB[j] = sr * 64 + (qp ^ (sr & 7)) * 8;
    }

    auto STAGE_A = [&](int h) {
        u16* lb = lds + (h & 3) * 8192;
        gll16(A + srcA[0] + h * 32, lb + ldsW[0]);
        gll16(A + srcA[1] + h * 32, lb + ldsW[1]);
    };
    auto STAGE_B = [&](int h) {
        u16* lb = lds + 32768 + (h & 3) * 8192;
        gll16(Bt + srcB[0] + h * 32, lb + ldsW[0]);
        gll16(Bt + srcB[1] + h * 32, lb + ldsW[1]);
    };

    f32x4 acc[8][4];
#pragma unroll
    for (int i = 0; i < 8; ++i)
#pragma unroll
        for (int j = 0; j < 4; ++j) acc[i][j] = (f32x4){0.f, 0.f, 0.f, 0.f};

    // prologue: halves 0,1,2 in flight (12 loads)
    STAGE_A(0); STAGE_B(0);
    STAGE_A(1); STAGE_B(1);
    STAGE_A(2); STAGE_B(2);

    for (int h = 0; h < NKH; ++h) {
        const u16* ab = lds + (h & 3) * 8192;
        const u16* bb = lds + 32768 + (h & 3) * 8192;

        // drain half h (oldest 4 of the outstanding ring loads)
        if (h <= NKH - 3)      { asm volatile("s_waitcnt vmcnt(8)" ::: "memory"); }
        else if (h == NKH - 2) { asm volatile("s_waitcnt vmcnt(4)" ::: "memory"); }
        else                   { asm volatile("s_waitcnt vmcnt(0)" ::: "memory"); }
        __builtin_amdgcn_sched_barrier(0);
        __builtin_amdgcn_s_barrier();      // publish half h; free slot (h-1)&3

        if (h + 3 < NKH) { STAGE_A(h + 3); STAGE_B(h + 3); }

        bf16x8 afr[8], bfr[4];
#pragma unroll
        for (int j = 0; j < 4; ++j) bfr[j] = *(const bf16x8*)(bb + offB[j]);
#pragma unroll
        for (int i = 0; i < 8; ++i) afr[i] = *(const bf16x8*)(ab + offA[i]);

        __builtin_amdgcn_s_setprio(1);
#pragma unroll
        for (int i = 0; i < 8; ++i)
#pragma unroll
            for (int j = 0; j < 4; ++j)
                acc[i][j] = __builtin_amdgcn_mfma_f32_16x16x32_bf16(afr[i], bfr[j], acc[i][j], 0, 0, 0);
        __builtin_amdgcn_s_setprio(0);
    }

#pragma unroll
    for (int i = 0; i < 8; ++i) {
#pragma unroll
        for (int j = 0; j < 4; ++j) {
            int mrow = m0 + wm * 128 + i * 16 + q * 4;
            int n = n0 + wn * 64 + j * 16 + l15;
#pragma unroll
            for (int r = 0; r < 4; ++r) {
                float v = acc[i][j][r];
                size_t m = (size_t)(mrow + r);
                if (n < DIN) o0[m * DIN + n] = f2bf(v);
                else if (n < DIN + CONVD) o1[m * CONVD + (n - DIN)] = f2bf(v);
                else if (n < DPROJ) o2[m * NH + (n - DIN - CONVD)] = f2bf(v);
            }
        }
    }
}

// ---------------- 128x256 deep-pipelined GEMM for the out-projection ----------------
// Same loop order as k_gemm8. 3 loads/half -> vmcnt(6)/3/0.
__global__ __launch_bounds__(512) void k_gemm8o(const u16* __restrict__ A, const u16* __restrict__ Bt,
                                                void* outF, const int* flagp) {
    constexpr int K = 2048;
    constexpr int NKH = K / 32;   // 64
    __shared__ __align__(16) u16 lds[49152];   // 96 KiB

    int tid = threadIdx.x;
    int lane = tid & 63, w = tid >> 6;
    int wm = w >> 2, wn = w & 3;
    int q = lane >> 4, l15 = lane & 15;

    int flat = blockIdx.x;                 // 256 blocks, bijective XCD swizzle
    int swz = (flat & 7) * 32 + (flat >> 3);
    int tm = swz >> 2, tn = swz & 3;
    int m0 = tm * 128, n0 = tn * 256;

    size_t srcA; int ldsWA;
    {
        int sr = tid >> 3, s = tid & 7;
        int qp = s ^ (sr & 7);
        int rr = sr * 2 + (qp >> 2), kg = qp & 3;
        srcA = (size_t)(m0 + rr) * K + kg * 8;
        ldsWA = (tid & ~63) * 8;
    }
    size_t srcB[2]; int ldsWB[2];
#pragma unroll
    for (int r = 0; r < 2; ++r) {
        int slotIdx = r * 512 + tid;
        int sr = slotIdx >> 3, s = slotIdx & 7;
        int qp = s ^ (sr & 7);
        int rr = sr * 2 + (qp >> 2), kg = qp & 3;
        srcB[r] = (size_t)(n0 + rr) * K + kg * 8;
        ldsWB[r] = (r * 512 + (tid & ~63)) * 8;
    }

    int offA[4], offB[4];
#pragma unroll
    for (int i = 0; i < 4; ++i) {
        int rl = wm * 64 + i * 16 + l15;
        int sr = rl >> 1, qp = q | ((rl & 1) << 2);
        offA[i] = sr * 64 + (qp ^ (sr & 7)) * 8;
    }
#pragma unroll
    for (int j = 0; j < 4; ++j) {
        int nl = wn * 64 + j * 16 + l15;
        int sr = nl >> 1, qp = q | ((nl & 1) << 2);
        offB[j] = sr * 64 + (qp ^ (sr & 7)) * 8;
    }

    auto STAGE = [&](int h) {
        u16* la = lds + (h & 3) * 4096;
        gll16(A + srcA + h * 32, la + ldsWA);
        u16* lb = lds + 16384 + (h & 3) * 8192;
        gll16(Bt + srcB[0] + h * 32, lb + ldsWB[0]);
        gll16(Bt + srcB[1] + h * 32, lb + ldsWB[1]);
    };

    f32x4 acc[4][4];
#pragma unroll
    for (int i = 0; i < 4; ++i)
#pragma unroll
        for (int j = 0; j < 4; ++j) acc[i][j] = (f32x4){0.f, 0.f, 0.f, 0.f};

    STAGE(0); STAGE(1); STAGE(2);

    for (int h = 0; h < NKH; ++h) {
        const u16* ab = lds + (h & 3) * 4096;
        const u16* bb = lds + 16384 + (h & 3) * 8192;

        if (h <= NKH - 3)      { asm volatile("s_waitcnt vmcnt(6)" ::: "memory"); }
        else if (h == NKH - 2) { asm volatile("s_waitcnt vmcnt(3)" ::: "memory"); }
        else                   { asm volatile("s_waitcnt vmcnt(0)" ::: "memory"); }
        __builtin_amdgcn_sched_barrier(0);
        __builtin_amdgcn_s_barrier();

        if (h + 3 < NKH) STAGE(h + 3);

        bf16x8 afr[4], bfr[4];
#pragma unroll
        for (int j = 0; j < 4; ++j) bfr[j] = *(const bf16x8*)(bb + offB[j]);
#pragma unroll
        for (int i = 0; i < 4; ++i) afr[i] = *(const bf16x8*)(ab + offA[i]);

        __builtin_amdgcn_s_setprio(1);
#pragma unroll
        for (int i = 0; i < 4; ++i)
#pragma unroll
            for (int j = 0; j < 4; ++j)
                acc[i][j] = __builtin_amdgcn_mfma_f32_16x16x32_bf16(afr[i], bfr[j], acc[i][j], 0, 0, 0);
        __builtin_amdgcn_s_setprio(0);
    }

    int fl = *flagp;
#pragma unroll
    for (int i = 0; i < 4; ++i) {
#pragma unroll
        for (int j = 0; j < 4; ++j) {
            int mrow = m0 + wm * 64 + i * 16 + q * 4;
            int n = n0 + wn * 64 + j * 16 + l15;
#pragma unroll
            for (int r = 0; r < 4; ++r)
                stout(outF, (size_t)(mrow + r) * 1024 + n, fl, acc[i][j][r]);
        }
    }
}

// ---------------- scores: G[bc][l][s] = C[l]·B[s], K=128, strided batch ----------------
__global__ __launch_bounds__(256) void k_scores(const u16* __restrict__ XCb, u16* G) {
    int bc = blockIdx.z;
    const u16* A  = XCb + (size_t)bc * CH * CONVD + DIN + DS;
    const u16* Bt = XCb + (size_t)bc * CH * CONVD + DIN;
    __shared__ __align__(16) u16 sA[4096];
    __shared__ __align__(16) u16 sB[4096];
    int t = threadIdx.x;
    int lane = t & 63, w = t >> 6;
    int wr = w >> 1, wc = w & 1;
    int m0 = blockIdx.y * 128, n0 = blockIdx.x * 128;

    const u16* gA[2]; const u16* gB[2];
    u16* lA[2]; u16* lB[2];
#pragma unroll
    for (int r = 0; r < 2; ++r) {
        int c = w * 128 + r * 64 + lane;
        int m = c >> 2;
        int ks = (c & 3) ^ ((m >> 1) & 3);
        gA[r] = A + (size_t)(m0 + m) * CONVD + ks * 8;
        gB[r] = Bt + (size_t)(n0 + m) * CONVD + ks * 8;
        lA[r] = sA + (size_t)(w * 128 + r * 64) * 8;
        lB[r] = sB + (size_t)(w * 128 + r * 64) * 8;
    }
    int q = lane >> 4, l15 = lane & 15;
    int offA[4], offB[4];
#pragma unroll
    for (int i = 0; i < 4; ++i) {
        int m = wr * 64 + i * 16 + l15;
        offA[i] = (m * 4 + (q ^ ((m >> 1) & 3))) * 8;
        int n = wc * 64 + i * 16 + l15;
        offB[i] = (n * 4 + (q ^ ((n >> 1) & 3))) * 8;
    }
    f32x4 acc[4][4];
#pragma unroll
    for (int i = 0; i < 4; ++i)
#pragma unroll
        for (int j = 0; j < 4; ++j) acc[i][j] = (f32x4){0.f, 0.f, 0.f, 0.f};

    for (int k0 = 0; k0 < 128; k0 += 32) {
        gll16(gA[0] + k0, lA[0]);
        gll16(gA[1] + k0, lA[1]);
        gll16(gB[0] + k0, lB[0]);
        gll16(gB[1] + k0, lB[1]);
        __syncthreads();
        bf16x8 af[4], bfv[4];
#pragma unroll
        for (int i = 0; i < 4; ++i) af[i] = *(const bf16x8*)(sA + offA[i]);
#pragma unroll
        for (int i = 0; i < 4; ++i) bfv[i] = *(const bf16x8*)(sB + offB[i]);
#pragma unroll
        for (int i = 0; i < 4; ++i)
#pragma unroll
            for (int j = 0; j < 4; ++j)
                acc[i][j] = __builtin_amdgcn_mfma_f32_16x16x32_bf16(af[i], bfv[j], acc[i][j], 0, 0, 0);
        __syncthreads();
    }
    size_t gb = (size_t)bc * 65536;
#pragma unroll
    for (int i = 0; i < 4; ++i) {
#pragma unroll
        for (int j = 0; j < 4; ++j) {
            int mrow = m0 + wr * 64 + i * 16 + q * 4;
            int n = n0 + wc * 64 + j * 16 + l15;
#pragma unroll
            for (int r = 0; r < 4; ++r)
                G[gb + (size_t)(mrow + r) * 256 + n] = f2bf(acc[i][j][r]);
        }
    }
}

// ---------------- dt softplus + per-chunk cumsum of dA (DTc chunk-major) ----------------
__global__ __launch_bounds__(256) void k_dtcum(const u16* DTraw, const void* dtb, const void* alog,
                                               const int* flagp, float* DTc, float* ACS, float* AL) {
    int fl = *flagp;
    int bid = blockIdx.x;                 // (b*16+c)*32+h
    int b = bid >> 9, c = (bid >> 5) & 15, h = bid & 31;
    int t = threadIdx.x;
    size_t bl = (size_t)b * LL + c * CH + t;
    float v = bf2f(DTraw[bl * NH + h]) + ldin(dtb, h, fl);
    float sp = (v > 20.f) ? v : log1pf(__expf(v));
    DTc[(size_t)bid * CH + t] = sp;
    float da = -__expf(ldin(alog, h, fl)) * sp;
    __shared__ float sc[256];
    sc[t] = da;
    __syncthreads();
    for (int off = 1; off < 256; off <<= 1) {
        float add = (t >= off) ? sc[t - off] : 0.f;
        __syncthreads();
        sc[t] += add;
        __syncthreads();
    }
    ACS[(size_t)bid * CH + t] = sc[t];
    if (t == 255) AL[bid] = sc[255];
}

// ---------------- causal depthwise conv (width 4) + silu, bf16x8 vectorized ----------------
// block 576 = 2 rows x 288 ch8-slots; grid 4096
__global__ __launch_bounds__(576) void k_conv(const u16* XBCr, const void* cw, const void* cb,
                                              const int* flagp, u16* XCb) {
    int fl = *flagp;
    int t = threadIdx.x;
    int half = (t >= 288) ? 1 : 0;
    int c8 = t - half * 288;              // 0..287
    size_t bl = (size_t)blockIdx.x * 2 + half;
    int l = (int)(bl & 4095);
    int ch0 = c8 * 8;
    float acc[8];
#pragma unroll
    for (int k = 0; k < 8; ++k) acc[k] = ldin(cb, ch0 + k, fl);
#pragma unroll
    for (int j = 0; j < 4; ++j) {
        int ls = l + j - 3;
        if (ls >= 0) {
            bf16x8 xv = *(const bf16x8*)(XBCr + (bl - 3 + j) * CONVD + ch0);
#pragma unroll
            for (int k = 0; k < 8; ++k)
                acc[k] += bf2f((u16)xv[k]) * ldin(cw, (size_t)(ch0 + k) * 4 + j, fl);
        }
    }
    bf16x8 ov;
#pragma unroll
    for (int k = 0; k < 8; ++k) {
        float a = acc[k];
        a = a / (1.f + __expf(-a));
        ov[k] = (short)f2bf(a);
    }
    *(bf16x8*)(XCb + bl * CONVD + ch0) = ov;
}

// ---------------- per-chunk states via MFMA: STt[p][n] = sum_l X[l,p]*wl[l] * B[l,n] ----------------
__global__ __launch_bounds__(256) void k_states(const u16* XCb, const float* DTc, const float* ACS,
                                                const float* AL, u16* STt) {
    int bid = blockIdx.x;            // (b*16+c)*32+h
    int b = bid >> 9, c = (bid >> 5) & 15, h = bid & 31;
    int t = threadIdx.x;
    size_t bL = (size_t)b * LL + c * CH;
    __shared__ float wl[256];
    __shared__ __align__(16) u16 Wt[128 * 38];   // B^T: [n][lk]
    __shared__ __align__(16) u16 Pt[64 * 38];    // X^T*wl: [p][lk]
    float al = AL[bid];
    wl[t] = __expf(al - ACS[(size_t)bid * CH + t]) * DTc[(size_t)bid * CH + t];
    __syncthreads();

    int lane = t & 63, w = t >> 6;
    int q = lane >> 4, l15 = lane & 15;
    f32x4 acc[8];
#pragma unroll
    for (int j = 0; j < 8; ++j) acc[j] = (f32x4){0.f, 0.f, 0.f, 0.f};

    for (int kt = 0; kt < 8; ++kt) {
        int l0 = kt * 32;
        if (kt) __syncthreads();
#pragma unroll
        for (int e = 0; e < 2; ++e) {
            int v = e * 256 + t;
            int lk = v >> 4, n8 = v & 15;
            bf16x8 bv = *(const bf16x8*)(XCb + (bL + l0 + lk) * CONVD + DIN + n8 * 8);
#pragma unroll
            for (int jj = 0; jj < 8; ++jj)
                Wt[(n8 * 8 + jj) * 38 + lk] = (u16)bv[jj];
        }
        {
            int lk = t >> 3, p8 = t & 7;
            float wv = wl[l0 + lk];
            bf16x8 xv = *(const bf16x8*)(XCb + (bL + l0 + lk) * CONVD + h * HD + p8 * 8);
#pragma unroll
            for (int jj = 0; jj < 8; ++jj)
                Pt[(p8 * 8 + jj) * 38 + lk] = f2bf(bf2f((u16)xv[jj]) * wv);
        }
        __syncthreads();
        bf16x8 af = *(const bf16x8*)&Pt[(w * 16 + l15) * 38 + q * 8];
#pragma unroll
        for (int j = 0; j < 8; ++j) {
            bf16x8 bv = *(const bf16x8*)&Wt[(j * 16 + l15) * 38 + q * 8];
            acc[j] = __builtin_amdgcn_mfma_f32_16x16x32_bf16(af, bv, acc[j], 0, 0, 0);
        }
    }
    size_t sbase = (size_t)bid * 8192;
#pragma unroll
    for (int j = 0; j < 8; ++j)
#pragma unroll
        for (int r = 0; r < 4; ++r)
            STt[sbase + (size_t)(w * 16 + q * 4 + r) * 128 + j * 16 + l15] = f2bf(acc[j][r]);
}

// ---------------- inter-chunk scan (in place; f32 carry; 4-way k-split) ----------------
__global__ __launch_bounds__(256) void k_scan(const float* AL, u16* ST) {
    int bid = blockIdx.x;  // b*128 + h*4 + seg
    int b = bid >> 7, h = (bid >> 2) & 31, seg = bid & 3;
    int t = threadIdx.x;
    float Pv[8];
#pragma unroll
    for (int k = 0; k < 8; ++k) Pv[k] = 0.f;
    for (int c = 0; c < NC; ++c) {
        int bch = (b * NC + c) * NH + h;
        float ga = __expf(AL[bch]);
        size_t base = (size_t)bch * 8192 + (size_t)seg * 8 * 256;
#pragma unroll
        for (int k = 0; k < 8; ++k) {
            size_t idx = base + (size_t)k * 256 + t;
            float s = bf2f(ST[idx]);
            ST[idx] = f2bf(Pv[k]);
            Pv[k] = ga * Pv[k] + s;
        }
    }
}

// ---------------- fused Y = decay-factored (C@P + G_below@X') + band direct ----------------
// grid (16, 2, 32): x = head-pair (n0=x*128), y = m-tile (m0=y*128), z = bc
__global__ __launch_bounds__(256, 4) void k_yfused(const u16* __restrict__ XCb, const float* DTc,
                                                   const float* ACS, const u16* __restrict__ G,
                                                   const u16* __restrict__ STt, u16* Yb) {
    int bc = blockIdx.z;
    int b = bc >> 4, c = bc & 15;
    int m0 = blockIdx.y * 128;
    int hq = blockIdx.x * 2;
    int t = threadIdx.x;
    size_t bL = (size_t)b * LL + c * CH;
    size_t gbase = (size_t)bc * 65536;

    __shared__ __align__(16) char smem[30720];
    u16* sA0 = (u16*)smem;
    u16* sA1 = (u16*)(smem + 8192);
    u16* sB  = (u16*)(smem + 16384);
    float* acs  = (float*)(smem + 24576);
    float* dts  = (float*)(smem + 26624);
    float* rowf = (float*)(smem + 28672);
    float* cfdt = (float*)(smem + 29696);

#pragma unroll
    for (int hh = 0; hh < 2; ++hh) {
        size_t bid = (size_t)bc * 32 + hq + hh;
        acs[hh * 256 + t] = ACS[bid * 256 + t];
        dts[hh * 256 + t] = DTc[bid * 256 + t];
    }
    __syncthreads();
    {
        int hh = t >> 7, lr = t & 127;
        float aref = acs[hh * 256 + m0];
        rowf[hh * 128 + lr] = __expf(acs[hh * 256 + m0 + lr] - aref);
        float cf = (lr < m0) ? __expf(aref - acs[hh * 256 + lr]) : 0.f;
        cfdt[hh * 128 + lr] = cf * dts[hh * 256 + lr];
    }
    __syncthreads();

    int lane = t & 63, w = t >> 6;
    int wr = w >> 1, wc = w & 1;
    int q = lane >> 4, l15 = lane & 15;
    int offA[4], offB[4];
#pragma unroll
    for (int i = 0; i < 4; ++i) {
        int m = wr * 64 + i * 16 + l15;
        offA[i] = (m * 4 + (q ^ ((m >> 1) & 3))) * 8;
        int n = wc * 64 + i * 16 + l15;
        offB[i] = (n * 4 + (q ^ ((n >> 1) & 3))) * 8;
    }
    f32x4 acc[4][4];
#pragma unroll
    for (int i = 0; i < 4; ++i)
#pragma unroll
        for (int j = 0; j < 4; ++j) acc[i][j] = (f32x4){0.f, 0.f, 0.f, 0.f};

    auto mfma_step = [&](const u16* A_, const u16* B_) {
        bf16x8 bfv[4];
#pragma unroll
        for (int j = 0; j < 4; ++j) bfv[j] = *(const bf16x8*)(B_ + offB[j]);
#pragma unroll
        for (int i = 0; i < 4; ++i) {
            bf16x8 af = *(const bf16x8*)(A_ + offA[i]);
#pragma unroll
            for (int j = 0; j < 4; ++j)
                acc[i][j] = __builtin_amdgcn_mfma_f32_16x16x32_bf16(af, bfv[j], acc[i][j], 0, 0, 0);
        }
    };

    int mm[2], kss[2];
    u16* lA[2]; u16* lB[2];
#pragma unroll
    for (int r = 0; r < 2; ++r) {
        int cc = w * 128 + r * 64 + lane;
        mm[r] = cc >> 2;
        kss[r] = (cc & 3) ^ ((mm[r] >> 1) & 3);
        lA[r] = sA0 + (size_t)(w * 128 + r * 64) * 8;
        lB[r] = sA1 + (size_t)(w * 128 + r * 64) * 8;
    }

    const u16* Ap = XCb + (size_t)bc * CH * CONVD + DIN + DS;
    const u16* Bp = STt + (size_t)bc * 262144;
    int n0 = blockIdx.x * 128;
    for (int k0 = 0; k0 < 128; k0 += 32) {
#pragma unroll
        for (int r = 0; r < 2; ++r) {
            gll16(Ap + (size_t)(m0 + mm[r]) * CONVD + kss[r] * 8 + k0, lA[r]);
            gll16(Bp + (size_t)(n0 + mm[r]) * 128   + kss[r] * 8 + k0, lB[r]);
        }
        __syncthreads();
        mfma_step(sA0, sA1);
        __syncthreads();
    }

    {
        float eb = __expf(acs[wc * 256 + m0]);
#pragma unroll
        for (int i = 0; i < 4; ++i)
#pragma unroll
            for (int j = 0; j < 4; ++j) {
                acc[i][j][0] *= eb; acc[i][j][1] *= eb;
                acc[i][j][2] *= eb; acc[i][j][3] *= eb;
            }
    }

    if (m0 == 128) {
        for (int s0 = 0; s0 < 128; s0 += 32) {
#pragma unroll
            for (int r = 0; r < 2; ++r)
                gll16(G + gbase + (size_t)(m0 + mm[r]) * 256 + s0 + kss[r] * 8, lA[r]);
#pragma unroll
            for (int e2 = 0; e2 < 2; ++e2) {
                int lin = (e2 * 256 + t) * 8;
                int k = lin >> 7, nn = lin & 127;
                int s = s0 + k;
                float wgt = cfdt[(nn >> 6) * 128 + s];
                bf16x8 xv = *(const bf16x8*)(XCb + (bL + s) * CONVD + hq * 64 + nn);
#pragma unroll
                for (int jj = 0; jj < 8; ++jj) {
                    int n2 = nn + jj;
                    sB[(n2 * 4 + ((k >> 3) ^ ((n2 >> 1) & 3))) * 8 + (k & 7)] =
                        f2bf(bf2f((u16)xv[jj]) * wgt);
                }
            }
            __syncthreads();
            mfma_step(sA0, sB);
            __syncthreads();
        }
    }

#pragma unroll
    for (int i = 0; i < 4; ++i) {
        int lb = wr * 64 + i * 16 + q * 4;
        const float* rf = rowf + wc * 128;
        float r0 = rf[lb], r1 = rf[lb + 1], r2 = rf[lb + 2], r3 = rf[lb + 3];
#pragma unroll
        for (int j = 0; j < 4; ++j) {
            acc[i][j][0] *= r0; acc[i][j][1] *= r1;
            acc[i][j][2] *= r2; acc[i][j][3] *= r3;
        }
    }

    for (int st = 0; st < 4; ++st) {
        int s0 = m0 + st * 32;
#pragma unroll
        for (int e2 = 0; e2 < 2; ++e2) {
            int id = e2 * 256 + t;
            int lr = id >> 2, kc = id & 3;
            int l = m0 + lr;
            bf16x8 gv = *(const bf16x8*)(G + gbase + (size_t)l * 256 + s0 + kc * 8);
            float a0l = acs[l], a1l = acs[256 + l];
            float4 a0a = *(const float4*)(acs + s0 + kc * 8);
            float4 a0b = *(const float4*)(acs + s0 + kc * 8 + 4);
            float4 a1a = *(const float4*)(acs + 256 + s0 + kc * 8);
            float4 a1b = *(const float4*)(acs + 256 + s0 + kc * 8 + 4);
            bf16x8 w0v, w1v;
#pragma unroll
            for (int jj = 0; jj < 8; ++jj) {
                int s = s0 + kc * 8 + jj;
                float as0 = (jj < 4) ? ((jj == 0) ? a0a.x : (jj == 1) ? a0a.y : (jj == 2) ? a0a.z : a0a.w)
                                     : ((jj == 4) ? a0b.x : (jj == 5) ? a0b.y : (jj == 6) ? a0b.z : a0b.w);
                float as1 = (jj < 4) ? ((jj == 0) ? a1a.x : (jj == 1) ? a1a.y : (jj == 2) ? a1a.z : a1a.w)
                                     : ((jj == 4) ? a1b.x : (jj == 5) ? a1b.y : (jj == 6) ? a1b.z : a1b.w);
                float g = bf2f((u16)gv[jj]);
                float w0 = 0.f, w1 = 0.f;
                if (l >= s) {
                    w0 = g * __expf(a0l - as0);
                    w1 = g * __expf(a1l - as1);
                }
                w0v[jj] = (short)f2bf(w0);
                w1v[jj] = (short)f2bf(w1);
            }
            int off = (lr * 4 + (kc ^ ((lr >> 1) & 3))) * 8;
            *(bf16x8*)(sA0 + off) = w0v;
            *(bf16x8*)(sA1 + off) = w1v;
        }
#pragma unroll
        for (int e2 = 0; e2 < 2; ++e2) {
            int lin = (e2 * 256 + t) * 8;
            int k = lin >> 7, nn = lin & 127;
            int s = s0 + k;
            float wgt = dts[(nn >> 6) * 256 + s];
            bf16x8 xv = *(const bf16x8*)(XCb + (bL + s) * CONVD + hq * 64 + nn);
#pragma unroll
            for (int jj = 0; jj < 8; ++jj) {
                int n2 = nn + jj;
                sB[(n2 * 4 + ((k >> 3) ^ ((n2 >> 1) & 3))) * 8 + (k & 7)] =
                    f2bf(bf2f((u16)xv[jj]) * wgt);
            }
        }
        __syncthreads();
        mfma_step(wc ? sA1 : sA0, sB);
        __syncthreads();
    }

#pragma unroll
    for (int i = 0; i < 4; ++i) {
        int l = m0 + wr * 64 + i * 16 + q * 4;
#pragma unroll
        for (int j = 0; j < 4; ++j) {
            int col = (hq + wc) * 64 + j * 16 + l15;
#pragma unroll
            for (int r = 0; r < 4; ++r)
                Yb[(bL + l + r) * (size_t)DIN + col] = f2bf(acc[i][j][r]);
        }
    }
}

// ---------------- layernorm * silu(z), in place on Yb (bf16x8 vectorized) ----------------
__global__ __launch_bounds__(256) void k_norm(u16* Yb, const u16* Zb, const void* nw, const int* flagp) {
    int fl = *flagp;
    size_t row = blockIdx.x;
    int t = threadIdx.x;
    size_t base = row * (size_t)DIN + (size_t)t * 8;
    bf16x8 yv = *(const bf16x8*)(Yb + base);
    float v[8];
#pragma unroll
    for (int k = 0; k < 8; ++k) v[k] = bf2f((u16)yv[k]);
    float s = 0.f;
#pragma unroll
    for (int k = 0; k < 8; ++k) s += v[k];
#pragma unroll
    for (int off = 32; off > 0; off >>= 1) s += __shfl_down(s, off);
    __shared__ float red[4];
    int wid = t >> 6, lid = t & 63;
    if (lid == 0) red[wid] = s;
    __syncthreads();
    float mu = (red[0] + red[1] + red[2] + red[3]) * (1.f / 2048.f);
    float d = 0.f;
#pragma unroll
    for (int k = 0; k < 8; ++k) { float e = v[k] - mu; d += e * e; }
#pragma unroll
    for (int off = 32; off > 0; off >>= 1) d += __shfl_down(d, off);
    __syncthreads();
    if (lid == 0) red[wid] = d;
    __syncthreads();
    float var = (red[0] + red[1] + red[2] + red[3]) * (1.f / 2048.f);
    float rs = rsqrtf(var + 1e-5f);
    bf16x8 zv = *(const bf16x8*)(Zb + base);
    bf16x8 ov;
#pragma unroll
    for (int k = 0; k < 8; ++k) {
        float z = bf2f((u16)zv[k]);
        float sz = z / (1.f + __expf(-z));
        ov[k] = (short)f2bf((v[k] - mu) * rs * ldin(nw, (size_t)t * 8 + k, fl) * sz);
    }
    *(bf16x8*)(Yb + base) = ov;
}

extern "C" void kernel_launch(void* const* d_in, const int* in_sizes, int n_in,
                              void* d_out, int out_size, void* d_ws, size_t ws_size,
                              hipStream_t stream) {
    const void* u    = d_in[0];
    const void* Win  = d_in[1];
    const void* cw   = d_in[2];
    const void* cb   = d_in[3];
    const void* dtb  = d_in[4];
    const void* alog = d_in[5];
    const void* nw   = d_in[6];
    const void* Wout = d_in[7];

    char* base = (char*)d_ws;
    int*  flag  = (int*)base;
    u16*  Zb    = (u16*)(base + 256);
    u16*  XBCr  = (u16*)(base + 33554688);
    u16*  XCb   = (u16*)(base + 71303424);
    u16*  ST    = (u16*)(base + 109052160);
    u16*  G     = (u16*)(base + 125829376);
    float* DTc  = (float*)(base + 130023680);
    float* ACS  = (float*)(base + 131072256);
    float* AL   = (float*)(base + 132120832);
    u16*  DTraw = (u16*)(base + 132124928);
    u16*  Yb    = XBCr;
    u16*  Ub    = (u16*)(base + 71303424);
    u16*  WinT  = (u16*)(base + 88080640);
    u16*  WoutT = (u16*)(base + 109052160);

    k_detect<<<1, 256, 0, stream>>>(u, flag);
    k_cast<<<8192, 256, 0, stream>>>(u, Ub, flag, 2097152);
    // WinT padded to 4608 rows (zero-filled) so the 256-wide N tiling is exact
    k_transpose<<<dim3(144, 32), 256, 0, stream>>>(Win, WinT, 1024, 4384, flag);
    k_gemm8<<<dim3(576), 512, 0, stream>>>(Ub, WinT, Zb, XBCr, DTraw);
    k_dtcum<<<1024, 256, 0, stream>>>(DTraw, dtb, alog, flag, DTc, ACS, AL);
    k_conv<<<dim3(4096), 576, 0, stream>>>(XBCr, cw, cb, flag, XCb);
    k_scores<<<dim3(2, 2, 32), 256, 0, stream>>>(XCb, G);
    k_states<<<1024, 256, 0, stream>>>(XCb, DTc, ACS, AL, ST);
    k_scan<<<256, 256, 0, stream>>>(AL, ST);
    k_yfused<<<dim3(16, 2, 32), 256, 0, stream>>>(XCb, DTc, ACS, G, ST, Yb);
    k_transpose<<<dim3(32, 64), 256, 0, stream>>>(Wout, WoutT, 2048, 1024, flag);
    k_norm<<<8192, 256, 0, stream>>>(Yb, Zb, nw, flag);
    k_gemm8o<<<dim3(256), 512, 0, stream>>>(Yb, WoutT, d_out, flag);
}

// Round 9
// 490.733 us; speedup vs baseline: 1.2067x; 1.2067x over previous
//
#include <hip/hip_runtime.h>
#include <hip/hip_bf16.h>

// Mamba2 fused block, MI355X. Round 15: revert k_conv to the proven scalar
// form (grid (9,8192)x256 — 73728 blocks of TLP; round-14's 4096x576 bf16x8
// rewrite was latency-bound at 193µs, 0.44TB/s). Keep round-14's GEMM loop
// order (drain -> BAR -> STAGE -> ds_read -> MFMA) in k_gemm8/k_gemm8o —
// the non-conv pie shrank ~60µs, confirming the same-side-of-barrier theory.

#define LL 4096
#define DPROJ 4384
#define CONVD 2304
#define DIN 2048
#define NH 32
#define HD 64
#define DS 128
#define CH 256
#define NC 16

typedef unsigned short u16;
typedef unsigned int u32;
typedef __attribute__((ext_vector_type(8))) short bf16x8;
typedef __attribute__((ext_vector_type(4))) float f32x4;

__device__ __forceinline__ float bf2f(u16 v) {
    u32 x = ((u32)v) << 16;
    float f; __builtin_memcpy(&f, &x, 4); return f;
}
__device__ __forceinline__ u16 f2bf(float f) {
    u32 x; __builtin_memcpy(&x, &f, 4);
    u32 r = (x + 0x7fffu + ((x >> 16) & 1u)) >> 16;   // RNE
    return (u16)r;
}
__device__ __forceinline__ float ldin(const void* p, size_t i, int bf) {
    if (bf) return bf2f(((const u16*)p)[i]);
    return ((const float*)p)[i];
}
__device__ __forceinline__ void stout(void* p, size_t i, int bf, float v) {
    if (bf) ((u16*)p)[i] = f2bf(v);
    else    ((float*)p)[i] = v;
}
__device__ __forceinline__ void gll16(const u16* g, u16* l) {
    __builtin_amdgcn_global_load_lds((const u32*)g, (u32*)l, 16, 0, 0);
}

// ---------------- dtype detector ----------------
__global__ void k_detect(const void* u, int* flag) {
    __shared__ int cnt;
    if (threadIdx.x == 0) cnt = 0;
    __syncthreads();
    u16 bits = ((const u16*)u)[2 * threadIdx.x];
    int e = (bits >> 7) & 0xff;
    int ok = (e >= 100 && e <= 141) ? 1 : 0;
    atomicAdd(&cnt, ok);
    __syncthreads();
    if (threadIdx.x == 0) *flag = (cnt > 128) ? 1 : 0;
}

// ---------------- cast to bf16 (identity when input already bf16) ----------------
__global__ void k_cast(const void* src, u16* dst, const int* flagp, int n4) {
    int fl = *flagp;
    size_t i = (size_t)blockIdx.x * 256 + threadIdx.x;
    if (i >= (size_t)n4) return;
    if (fl) {
        ((u32*)dst)[i * 2]     = ((const u32*)src)[i * 2];
        ((u32*)dst)[i * 2 + 1] = ((const u32*)src)[i * 2 + 1];
    } else {
        float4 v = ((const float4*)src)[i];
        dst[i * 4 + 0] = f2bf(v.x); dst[i * 4 + 1] = f2bf(v.y);
        dst[i * 4 + 2] = f2bf(v.z); dst[i * 4 + 3] = f2bf(v.w);
    }
}

// ---------------- transpose + cast: src[R][Cc] -> dst[Cpad][R] bf16, zero-fill ----------------
__global__ __launch_bounds__(256) void k_transpose(const void* src, u16* dst,
                                                   int R, int Cc, const int* flagp) {
    int fl = *flagp;
    __shared__ float tile[32][33];
    int r0 = blockIdx.y * 32, c0 = blockIdx.x * 32;
    int t = threadIdx.x;
    int tr = t >> 5, tc = t & 31;
#pragma unroll
    for (int i = 0; i < 4; ++i) {
        int r = r0 + tr + i * 8, c = c0 + tc;
        float v = 0.f;
        if (c < Cc) v = ldin(src, (size_t)r * Cc + c, fl);
        tile[tr + i * 8][tc] = v;
    }
    __syncthreads();
#pragma unroll
    for (int i = 0; i < 4; ++i) {
        int c = c0 + tr + i * 8, r = r0 + tc;
        dst[(size_t)c * R + r] = f2bf(tile[tc][tr + i * 8]);
    }
}

// ---------------- 256x256 deep-pipelined MFMA GEMM for the in-projection ----------------
// LDS: ring of 4 K-half slots per matrix (slot = h&3). A [0..32768) hw,
// B [32768..65536) hw. Super-row (2 rows) = 64 hw; slot16 = (q|(par<<2))^(sr&7).
// Loop order: drain(h) -> BAR -> STAGE(h+3) -> ds_read(h) -> MFMA(h).
__global__ __launch_bounds__(512) void k_gemm8(const u16* __restrict__ A, const u16* __restrict__ Bt,
                                               u16* o0, u16* o1, u16* o2) {
    constexpr int K = 1024;
    constexpr int NKH = K / 32;   // 32 K-halves
    __shared__ __align__(16) u16 lds[65536];   // 128 KiB

    int tid = threadIdx.x;
    int lane = tid & 63, w = tid >> 6;
    int wm = w >> 2, wn = w & 3;
    int q = lane >> 4, l15 = lane & 15;

    int flat = blockIdx.x;                 // 576 blocks, 576 % 8 == 0 -> bijective XCD swizzle
    int swz = (flat & 7) * 72 + (flat >> 3);
    int tm = swz / 18, tn = swz % 18;
    int m0 = tm * 256, n0 = tn * 256;

    size_t srcA[2], srcB[2];
    int ldsW[2];
#pragma unroll
    for (int r = 0; r < 2; ++r) {
        int slotIdx = r * 512 + tid;
        int sr = slotIdx >> 3, s = slotIdx & 7;
        int qp = s ^ (sr & 7);
        int rr = sr * 2 + (qp >> 2), kg = qp & 3;
        srcA[r] = (size_t)(m0 + rr) * K + kg * 8;
        srcB[r] = (size_t)(n0 + rr) * K + kg * 8;
        ldsW[r] = (r * 512 + (tid & ~63)) * 8;
    }

    int offA[8], offB[4];
#pragma unroll
    for (int i = 0; i < 8; ++i) {
        int rl = wm * 128 + i * 16 + l15;
        int sr = rl >> 1, qp = q | ((rl & 1) << 2);
        offA[i] = sr * 64 + (qp ^ (sr & 7)) * 8;
    }
#pragma unroll
    for (int j = 0; j < 4; ++j) {
        int nl = wn * 64 + j * 16 + l15;
        int sr = nl >> 1, qp = q | ((nl & 1) << 2);
        offB[j] = sr * 64 + (qp ^ (sr & 7)) * 8;
    }

    auto STAGE_A = [&](int h) {
        u16* lb = lds + (h & 3) * 8192;
        gll16(A + srcA[0] + h * 32, lb + ldsW[0]);
        gll16(A + srcA[1] + h * 32, lb + ldsW[1]);
    };
    auto STAGE_B = [&](int h) {
        u16* lb = lds + 32768 + (h & 3) * 8192;
        gll16(Bt + srcB[0] + h * 32, lb + ldsW[0]);
        gll16(Bt + srcB[1] + h * 32, lb + ldsW[1]);
    };

    f32x4 acc[8][4];
#pragma unroll
    for (int i = 0; i < 8; ++i)
#pragma unroll
        for (int j = 0; j < 4; ++j) acc[i][j] = (f32x4){0.f, 0.f, 0.f, 0.f};

    // prologue: halves 0,1,2 in flight (12 loads)
    STAGE_A(0); STAGE_B(0);
    STAGE_A(1); STAGE_B(1);
    STAGE_A(2); STAGE_B(2);

    for (int h = 0; h < NKH; ++h) {
        const u16* ab = lds + (h & 3) * 8192;
        const u16* bb = lds + 32768 + (h & 3) * 8192;

        // drain half h (oldest 4 of the outstanding ring loads)
        if (h <= NKH - 3)      { asm volatile("s_waitcnt vmcnt(8)" ::: "memory"); }
        else if (h == NKH - 2) { asm volatile("s_waitcnt vmcnt(4)" ::: "memory"); }
        else                   { asm volatile("s_waitcnt vmcnt(0)" ::: "memory"); }
        __builtin_amdgcn_sched_barrier(0);
        __builtin_amdgcn_s_barrier();      // publish half h; free slot (h-1)&3

        if (h + 3 < NKH) { STAGE_A(h + 3); STAGE_B(h + 3); }

        bf16x8 afr[8], bfr[4];
#pragma unroll
        for (int j = 0; j < 4; ++j) bfr[j] = *(const bf16x8*)(bb + offB[j]);
#pragma unroll
        for (int i = 0; i < 8; ++i) afr[i] = *(const bf16x8*)(ab + offA[i]);

        __builtin_amdgcn_s_setprio(1);
#pragma unroll
        for (int i = 0; i < 8; ++i)
#pragma unroll
            for (int j = 0; j < 4; ++j)
                acc[i][j] = __builtin_amdgcn_mfma_f32_16x16x32_bf16(afr[i], bfr[j], acc[i][j], 0, 0, 0);
        __builtin_amdgcn_s_setprio(0);
    }

#pragma unroll
    for (int i = 0; i < 8; ++i) {
#pragma unroll
        for (int j = 0; j < 4; ++j) {
            int mrow = m0 + wm * 128 + i * 16 + q * 4;
            int n = n0 + wn * 64 + j * 16 + l15;
#pragma unroll
            for (int r = 0; r < 4; ++r) {
                float v = acc[i][j][r];
                size_t m = (size_t)(mrow + r);
                if (n < DIN) o0[m * DIN + n] = f2bf(v);
                else if (n < DIN + CONVD) o1[m * CONVD + (n - DIN)] = f2bf(v);
                else if (n < DPROJ) o2[m * NH + (n - DIN - CONVD)] = f2bf(v);
            }
        }
    }
}

// ---------------- 128x256 deep-pipelined GEMM for the out-projection ----------------
// Same loop order as k_gemm8. 3 loads/half -> vmcnt(6)/3/0.
__global__ __launch_bounds__(512) void k_gemm8o(const u16* __restrict__ A, const u16* __restrict__ Bt,
                                                void* outF, const int* flagp) {
    constexpr int K = 2048;
    constexpr int NKH = K / 32;   // 64
    __shared__ __align__(16) u16 lds[49152];   // 96 KiB

    int tid = threadIdx.x;
    int lane = tid & 63, w = tid >> 6;
    int wm = w >> 2, wn = w & 3;
    int q = lane >> 4, l15 = lane & 15;

    int flat = blockIdx.x;                 // 256 blocks, bijective XCD swizzle
    int swz = (flat & 7) * 32 + (flat >> 3);
    int tm = swz >> 2, tn = swz & 3;
    int m0 = tm * 128, n0 = tn * 256;

    size_t srcA; int ldsWA;
    {
        int sr = tid >> 3, s = tid & 7;
        int qp = s ^ (sr & 7);
        int rr = sr * 2 + (qp >> 2), kg = qp & 3;
        srcA = (size_t)(m0 + rr) * K + kg * 8;
        ldsWA = (tid & ~63) * 8;
    }
    size_t srcB[2]; int ldsWB[2];
#pragma unroll
    for (int r = 0; r < 2; ++r) {
        int slotIdx = r * 512 + tid;
        int sr = slotIdx >> 3, s = slotIdx & 7;
        int qp = s ^ (sr & 7);
        int rr = sr * 2 + (qp >> 2), kg = qp & 3;
        srcB[r] = (size_t)(n0 + rr) * K + kg * 8;
        ldsWB[r] = (r * 512 + (tid & ~63)) * 8;
    }

    int offA[4], offB[4];
#pragma unroll
    for (int i = 0; i < 4; ++i) {
        int rl = wm * 64 + i * 16 + l15;
        int sr = rl >> 1, qp = q | ((rl & 1) << 2);
        offA[i] = sr * 64 + (qp ^ (sr & 7)) * 8;
    }
#pragma unroll
    for (int j = 0; j < 4; ++j) {
        int nl = wn * 64 + j * 16 + l15;
        int sr = nl >> 1, qp = q | ((nl & 1) << 2);
        offB[j] = sr * 64 + (qp ^ (sr & 7)) * 8;
    }

    auto STAGE = [&](int h) {
        u16* la = lds + (h & 3) * 4096;
        gll16(A + srcA + h * 32, la + ldsWA);
        u16* lb = lds + 16384 + (h & 3) * 8192;
        gll16(Bt + srcB[0] + h * 32, lb + ldsWB[0]);
        gll16(Bt + srcB[1] + h * 32, lb + ldsWB[1]);
    };

    f32x4 acc[4][4];
#pragma unroll
    for (int i = 0; i < 4; ++i)
#pragma unroll
        for (int j = 0; j < 4; ++j) acc[i][j] = (f32x4){0.f, 0.f, 0.f, 0.f};

    STAGE(0); STAGE(1); STAGE(2);

    for (int h = 0; h < NKH; ++h) {
        const u16* ab = lds + (h & 3) * 4096;
        const u16* bb = lds + 16384 + (h & 3) * 8192;

        if (h <= NKH - 3)      { asm volatile("s_waitcnt vmcnt(6)" ::: "memory"); }
        else if (h == NKH - 2) { asm volatile("s_waitcnt vmcnt(3)" ::: "memory"); }
        else                   { asm volatile("s_waitcnt vmcnt(0)" ::: "memory"); }
        __builtin_amdgcn_sched_barrier(0);
        __builtin_amdgcn_s_barrier();

        if (h + 3 < NKH) STAGE(h + 3);

        bf16x8 afr[4], bfr[4];
#pragma unroll
        for (int j = 0; j < 4; ++j) bfr[j] = *(const bf16x8*)(bb + offB[j]);
#pragma unroll
        for (int i = 0; i < 4; ++i) afr[i] = *(const bf16x8*)(ab + offA[i]);

        __builtin_amdgcn_s_setprio(1);
#pragma unroll
        for (int i = 0; i < 4; ++i)
#pragma unroll
            for (int j = 0; j < 4; ++j)
                acc[i][j] = __builtin_amdgcn_mfma_f32_16x16x32_bf16(afr[i], bfr[j], acc[i][j], 0, 0, 0);
        __builtin_amdgcn_s_setprio(0);
    }

    int fl = *flagp;
#pragma unroll
    for (int i = 0; i < 4; ++i) {
#pragma unroll
        for (int j = 0; j < 4; ++j) {
            int mrow = m0 + wm * 64 + i * 16 + q * 4;
            int n = n0 + wn * 64 + j * 16 + l15;
#pragma unroll
            for (int r = 0; r < 4; ++r)
                stout(outF, (size_t)(mrow + r) * 1024 + n, fl, acc[i][j][r]);
        }
    }
}

// ---------------- scores: G[bc][l][s] = C[l]·B[s], K=128, strided batch ----------------
__global__ __launch_bounds__(256) void k_scores(const u16* __restrict__ XCb, u16* G) {
    int bc = blockIdx.z;
    const u16* A  = XCb + (size_t)bc * CH * CONVD + DIN + DS;
    const u16* Bt = XCb + (size_t)bc * CH * CONVD + DIN;
    __shared__ __align__(16) u16 sA[4096];
    __shared__ __align__(16) u16 sB[4096];
    int t = threadIdx.x;
    int lane = t & 63, w = t >> 6;
    int wr = w >> 1, wc = w & 1;
    int m0 = blockIdx.y * 128, n0 = blockIdx.x * 128;

    const u16* gA[2]; const u16* gB[2];
    u16* lA[2]; u16* lB[2];
#pragma unroll
    for (int r = 0; r < 2; ++r) {
        int c = w * 128 + r * 64 + lane;
        int m = c >> 2;
        int ks = (c & 3) ^ ((m >> 1) & 3);
        gA[r] = A + (size_t)(m0 + m) * CONVD + ks * 8;
        gB[r] = Bt + (size_t)(n0 + m) * CONVD + ks * 8;
        lA[r] = sA + (size_t)(w * 128 + r * 64) * 8;
        lB[r] = sB + (size_t)(w * 128 + r * 64) * 8;
    }
    int q = lane >> 4, l15 = lane & 15;
    int offA[4], offB[4];
#pragma unroll
    for (int i = 0; i < 4; ++i) {
        int m = wr * 64 + i * 16 + l15;
        offA[i] = (m * 4 + (q ^ ((m >> 1) & 3))) * 8;
        int n = wc * 64 + i * 16 + l15;
        offB[i] = (n * 4 + (q ^ ((n >> 1) & 3))) * 8;
    }
    f32x4 acc[4][4];
#pragma unroll
    for (int i = 0; i < 4; ++i)
#pragma unroll
        for (int j = 0; j < 4; ++j) acc[i][j] = (f32x4){0.f, 0.f, 0.f, 0.f};

    for (int k0 = 0; k0 < 128; k0 += 32) {
        gll16(gA[0] + k0, lA[0]);
        gll16(gA[1] + k0, lA[1]);
        gll16(gB[0] + k0, lB[0]);
        gll16(gB[1] + k0, lB[1]);
        __syncthreads();
        bf16x8 af[4], bfv[4];
#pragma unroll
        for (int i = 0; i < 4; ++i) af[i] = *(const bf16x8*)(sA + offA[i]);
#pragma unroll
        for (int i = 0; i < 4; ++i) bfv[i] = *(const bf16x8*)(sB + offB[i]);
#pragma unroll
        for (int i = 0; i < 4; ++i)
#pragma unroll
            for (int j = 0; j < 4; ++j)
                acc[i][j] = __builtin_amdgcn_mfma_f32_16x16x32_bf16(af[i], bfv[j], acc[i][j], 0, 0, 0);
        __syncthreads();
    }
    size_t gb = (size_t)bc * 65536;
#pragma unroll
    for (int i = 0; i < 4; ++i) {
#pragma unroll
        for (int j = 0; j < 4; ++j) {
            int mrow = m0 + wr * 64 + i * 16 + q * 4;
            int n = n0 + wc * 64 + j * 16 + l15;
#pragma unroll
            for (int r = 0; r < 4; ++r)
                G[gb + (size_t)(mrow + r) * 256 + n] = f2bf(acc[i][j][r]);
        }
    }
}

// ---------------- dt softplus + per-chunk cumsum of dA (DTc chunk-major) ----------------
__global__ __launch_bounds__(256) void k_dtcum(const u16* DTraw, const void* dtb, const void* alog,
                                               const int* flagp, float* DTc, float* ACS, float* AL) {
    int fl = *flagp;
    int bid = blockIdx.x;                 // (b*16+c)*32+h
    int b = bid >> 9, c = (bid >> 5) & 15, h = bid & 31;
    int t = threadIdx.x;
    size_t bl = (size_t)b * LL + c * CH + t;
    float v = bf2f(DTraw[bl * NH + h]) + ldin(dtb, h, fl);
    float sp = (v > 20.f) ? v : log1pf(__expf(v));
    DTc[(size_t)bid * CH + t] = sp;
    float da = -__expf(ldin(alog, h, fl)) * sp;
    __shared__ float sc[256];
    sc[t] = da;
    __syncthreads();
    for (int off = 1; off < 256; off <<= 1) {
        float add = (t >= off) ? sc[t - off] : 0.f;
        __syncthreads();
        sc[t] += add;
        __syncthreads();
    }
    ACS[(size_t)bid * CH + t] = sc[t];
    if (t == 255) AL[bid] = sc[255];
}

// ---------------- causal depthwise conv (width 4) + silu (proven scalar form) ----------------
__global__ void k_conv(const u16* XBCr, const void* cw, const void* cb, const int* flagp, u16* XCb) {
    int fl = *flagp;
    int ch = blockIdx.x * 256 + threadIdx.x;   // 0..2303 (grid.x = 9)
    size_t bl = blockIdx.y;                    // 0..8191
    int l = (int)(bl & 4095);
    float acc = ldin(cb, ch, fl);
#pragma unroll
    for (int j = 0; j < 4; ++j) {
        int ls = l + j - 3;
        if (ls >= 0)
            acc += bf2f(XBCr[(bl - l + ls) * CONVD + ch]) * ldin(cw, (size_t)ch * 4 + j, fl);
    }
    acc = acc / (1.f + __expf(-acc));
    XCb[bl * CONVD + ch] = f2bf(acc);
}

// ---------------- per-chunk states via MFMA: STt[p][n] = sum_l X[l,p]*wl[l] * B[l,n] ----------------
__global__ __launch_bounds__(256) void k_states(const u16* XCb, const float* DTc, const float* ACS,
                                                const float* AL, u16* STt) {
    int bid = blockIdx.x;            // (b*16+c)*32+h
    int b = bid >> 9, c = (bid >> 5) & 15, h = bid & 31;
    int t = threadIdx.x;
    size_t bL = (size_t)b * LL + c * CH;
    __shared__ float wl[256];
    __shared__ __align__(16) u16 Wt[128 * 38];   // B^T: [n][lk]
    __shared__ __align__(16) u16 Pt[64 * 38];    // X^T*wl: [p][lk]
    float al = AL[bid];
    wl[t] = __expf(al - ACS[(size_t)bid * CH + t]) * DTc[(size_t)bid * CH + t];
    __syncthreads();

    int lane = t & 63, w = t >> 6;
    int q = lane >> 4, l15 = lane & 15;
    f32x4 acc[8];
#pragma unroll
    for (int j = 0; j < 8; ++j) acc[j] = (f32x4){0.f, 0.f, 0.f, 0.f};

    for (int kt = 0; kt < 8; ++kt) {
        int l0 = kt * 32;
        if (kt) __syncthreads();
#pragma unroll
        for (int e = 0; e < 2; ++e) {
            int v = e * 256 + t;
            int lk = v >> 4, n8 = v & 15;
            bf16x8 bv = *(const bf16x8*)(XCb + (bL + l0 + lk) * CONVD + DIN + n8 * 8);
#pragma unroll
            for (int jj = 0; jj < 8; ++jj)
                Wt[(n8 * 8 + jj) * 38 + lk] = (u16)bv[jj];
        }
        {
            int lk = t >> 3, p8 = t & 7;
            float wv = wl[l0 + lk];
            bf16x8 xv = *(const bf16x8*)(XCb + (bL + l0 + lk) * CONVD + h * HD + p8 * 8);
#pragma unroll
            for (int jj = 0; jj < 8; ++jj)
                Pt[(p8 * 8 + jj) * 38 + lk] = f2bf(bf2f((u16)xv[jj]) * wv);
        }
        __syncthreads();
        bf16x8 af = *(const bf16x8*)&Pt[(w * 16 + l15) * 38 + q * 8];
#pragma unroll
        for (int j = 0; j < 8; ++j) {
            bf16x8 bv = *(const bf16x8*)&Wt[(j * 16 + l15) * 38 + q * 8];
            acc[j] = __builtin_amdgcn_mfma_f32_16x16x32_bf16(af, bv, acc[j], 0, 0, 0);
        }
    }
    size_t sbase = (size_t)bid * 8192;
#pragma unroll
    for (int j = 0; j < 8; ++j)
#pragma unroll
        for (int r = 0; r < 4; ++r)
            STt[sbase + (size_t)(w * 16 + q * 4 + r) * 128 + j * 16 + l15] = f2bf(acc[j][r]);
}

// ---------------- inter-chunk scan (in place; f32 carry; 4-way k-split) ----------------
__global__ __launch_bounds__(256) void k_scan(const float* AL, u16* ST) {
    int bid = blockIdx.x;  // b*128 + h*4 + seg
    int b = bid >> 7, h = (bid >> 2) & 31, seg = bid & 3;
    int t = threadIdx.x;
    float Pv[8];
#pragma unroll
    for (int k = 0; k < 8; ++k) Pv[k] = 0.f;
    for (int c = 0; c < NC; ++c) {
        int bch = (b * NC + c) * NH + h;
        float ga = __expf(AL[bch]);
        size_t base = (size_t)bch * 8192 + (size_t)seg * 8 * 256;
#pragma unroll
        for (int k = 0; k < 8; ++k) {
            size_t idx = base + (size_t)k * 256 + t;
            float s = bf2f(ST[idx]);
            ST[idx] = f2bf(Pv[k]);
            Pv[k] = ga * Pv[k] + s;
        }
    }
}

// ---------------- fused Y = decay-factored (C@P + G_below@X') + band direct ----------------
// grid (16, 2, 32): x = head-pair (n0=x*128), y = m-tile (m0=y*128), z = bc
__global__ __launch_bounds__(256, 4) void k_yfused(const u16* __restrict__ XCb, const float* DTc,
                                                   const float* ACS, const u16* __restrict__ G,
                                                   const u16* __restrict__ STt, u16* Yb) {
    int bc = blockIdx.z;
    int b = bc >> 4, c = bc & 15;
    int m0 = blockIdx.y * 128;
    int hq = blockIdx.x * 2;
    int t = threadIdx.x;
    size_t bL = (size_t)b * LL + c * CH;
    size_t gbase = (size_t)bc * 65536;

    __shared__ __align__(16) char smem[30720];
    u16* sA0 = (u16*)smem;
    u16* sA1 = (u16*)(smem + 8192);
    u16* sB  = (u16*)(smem + 16384);
    float* acs  = (float*)(smem + 24576);
    float* dts  = (float*)(smem + 26624);
    float* rowf = (float*)(smem + 28672);
    float* cfdt = (float*)(smem + 29696);

#pragma unroll
    for (int hh = 0; hh < 2; ++hh) {
        size_t bid = (size_t)bc * 32 + hq + hh;
        acs[hh * 256 + t] = ACS[bid * 256 + t];
        dts[hh * 256 + t] = DTc[bid * 256 + t];
    }
    __syncthreads();
    {
        int hh = t >> 7, lr = t & 127;
        float aref = acs[hh * 256 + m0];
        rowf[hh * 128 + lr] = __expf(acs[hh * 256 + m0 + lr] - aref);
        float cf = (lr < m0) ? __expf(aref - acs[hh * 256 + lr]) : 0.f;
        cfdt[hh * 128 + lr] = cf * dts[hh * 256 + lr];
    }
    __syncthreads();

    int lane = t & 63, w = t >> 6;
    int wr = w >> 1, wc = w & 1;
    int q = lane >> 4, l15 = lane & 15;
    int offA[4], offB[4];
#pragma unroll
    for (int i = 0; i < 4; ++i) {
        int m = wr * 64 + i * 16 + l15;
        offA[i] = (m * 4 + (q ^ ((m >> 1) & 3))) * 8;
        int n = wc * 64 + i * 16 + l15;
        offB[i] = (n * 4 + (q ^ ((n >> 1) & 3))) * 8;
    }
    f32x4 acc[4][4];
#pragma unroll
    for (int i = 0; i < 4; ++i)
#pragma unroll
        for (int j = 0; j < 4; ++j) acc[i][j] = (f32x4){0.f, 0.f, 0.f, 0.f};

    auto mfma_step = [&](const u16* A_, const u16* B_) {
        bf16x8 bfv[4];
#pragma unroll
        for (int j = 0; j < 4; ++j) bfv[j] = *(const bf16x8*)(B_ + offB[j]);
#pragma unroll
        for (int i = 0; i < 4; ++i) {
            bf16x8 af = *(const bf16x8*)(A_ + offA[i]);
#pragma unroll
            for (int j = 0; j < 4; ++j)
                acc[i][j] = __builtin_amdgcn_mfma_f32_16x16x32_bf16(af, bfv[j], acc[i][j], 0, 0, 0);
        }
    };

    int mm[2], kss[2];
    u16* lA[2]; u16* lB[2];
#pragma unroll
    for (int r = 0; r < 2; ++r) {
        int cc = w * 128 + r * 64 + lane;
        mm[r] = cc >> 2;
        kss[r] = (cc & 3) ^ ((mm[r] >> 1) & 3);
        lA[r] = sA0 + (size_t)(w * 128 + r * 64) * 8;
        lB[r] = sA1 + (size_t)(w * 128 + r * 64) * 8;
    }

    const u16* Ap = XCb + (size_t)bc * CH * CONVD + DIN + DS;
    const u16* Bp = STt + (size_t)bc * 262144;
    int n0 = blockIdx.x * 128;
    for (int k0 = 0; k0 < 128; k0 += 32) {
#pragma unroll
        for (int r = 0; r < 2; ++r) {
            gll16(Ap + (size_t)(m0 + mm[r]) * CONVD + kss[r] * 8 + k0, lA[r]);
            gll16(Bp + (size_t)(n0 + mm[r]) * 128   + kss[r] * 8 + k0, lB[r]);
        }
        __syncthreads();
        mfma_step(sA0, sA1);
        __syncthreads();
    }

    {
        float eb = __expf(acs[wc * 256 + m0]);
#pragma unroll
        for (int i = 0; i < 4; ++i)
#pragma unroll
            for (int j = 0; j < 4; ++j) {
                acc[i][j][0] *= eb; acc[i][j][1] *= eb;
                acc[i][j][2] *= eb; acc[i][j][3] *= eb;
            }
    }

    if (m0 == 128) {
        for (int s0 = 0; s0 < 128; s0 += 32) {
#pragma unroll
            for (int r = 0; r < 2; ++r)
                gll16(G + gbase + (size_t)(m0 + mm[r]) * 256 + s0 + kss[r] * 8, lA[r]);
#pragma unroll
            for (int e2 = 0; e2 < 2; ++e2) {
                int lin = (e2 * 256 + t) * 8;
                int k = lin >> 7, nn = lin & 127;
                int s = s0 + k;
                float wgt = cfdt[(nn >> 6) * 128 + s];
                bf16x8 xv = *(const bf16x8*)(XCb + (bL + s) * CONVD + hq * 64 + nn);
#pragma unroll
                for (int jj = 0; jj < 8; ++jj) {
                    int n2 = nn + jj;
                    sB[(n2 * 4 + ((k >> 3) ^ ((n2 >> 1) & 3))) * 8 + (k & 7)] =
                        f2bf(bf2f((u16)xv[jj]) * wgt);
                }
            }
            __syncthreads();
            mfma_step(sA0, sB);
            __syncthreads();
        }
    }

#pragma unroll
    for (int i = 0; i < 4; ++i) {
        int lb = wr * 64 + i * 16 + q * 4;
        const float* rf = rowf + wc * 128;
        float r0 = rf[lb], r1 = rf[lb + 1], r2 = rf[lb + 2], r3 = rf[lb + 3];
#pragma unroll
        for (int j = 0; j < 4; ++j) {
            acc[i][j][0] *= r0; acc[i][j][1] *= r1;
            acc[i][j][2] *= r2; acc[i][j][3] *= r3;
        }
    }

    for (int st = 0; st < 4; ++st) {
        int s0 = m0 + st * 32;
#pragma unroll
        for (int e2 = 0; e2 < 2; ++e2) {
            int id = e2 * 256 + t;
            int lr = id >> 2, kc = id & 3;
            int l = m0 + lr;
            bf16x8 gv = *(const bf16x8*)(G + gbase + (size_t)l * 256 + s0 + kc * 8);
            float a0l = acs[l], a1l = acs[256 + l];
            float4 a0a = *(const float4*)(acs + s0 + kc * 8);
            float4 a0b = *(const float4*)(acs + s0 + kc * 8 + 4);
            float4 a1a = *(const float4*)(acs + 256 + s0 + kc * 8);
            float4 a1b = *(const float4*)(acs + 256 + s0 + kc * 8 + 4);
            bf16x8 w0v, w1v;
#pragma unroll
            for (int jj = 0; jj < 8; ++jj) {
                int s = s0 + kc * 8 + jj;
                float as0 = (jj < 4) ? ((jj == 0) ? a0a.x : (jj == 1) ? a0a.y : (jj == 2) ? a0a.z : a0a.w)
                                     : ((jj == 4) ? a0b.x : (jj == 5) ? a0b.y : (jj == 6) ? a0b.z : a0b.w);
                float as1 = (jj < 4) ? ((jj == 0) ? a1a.x : (jj == 1) ? a1a.y : (jj == 2) ? a1a.z : a1a.w)
                                     : ((jj == 4) ? a1b.x : (jj == 5) ? a1b.y : (jj == 6) ? a1b.z : a1b.w);
                float g = bf2f((u16)gv[jj]);
                float w0 = 0.f, w1 = 0.f;
                if (l >= s) {
                    w0 = g * __expf(a0l - as0);
                    w1 = g * __expf(a1l - as1);
                }
                w0v[jj] = (short)f2bf(w0);
                w1v[jj] = (short)f2bf(w1);
            }
            int off = (lr * 4 + (kc ^ ((lr >> 1) & 3))) * 8;
            *(bf16x8*)(sA0 + off) = w0v;
            *(bf16x8*)(sA1 + off) = w1v;
        }
#pragma unroll
        for (int e2 = 0; e2 < 2; ++e2) {
            int lin = (e2 * 256 + t) * 8;
            int k = lin >> 7, nn = lin & 127;
            int s = s0 + k;
            float wgt = dts[(nn >> 6) * 256 + s];
            bf16x8 xv = *(const bf16x8*)(XCb + (bL + s) * CONVD + hq * 64 + nn);
#pragma unroll
            for (int jj = 0; jj < 8; ++jj) {
                int n2 = nn + jj;
                sB[(n2 * 4 + ((k >> 3) ^ ((n2 >> 1) & 3))) * 8 + (k & 7)] =
                    f2bf(bf2f((u16)xv[jj]) * wgt);
            }
        }
        __syncthreads();
        mfma_step(wc ? sA1 : sA0, sB);
        __syncthreads();
    }

#pragma unroll
    for (int i = 0; i < 4; ++i) {
        int l = m0 + wr * 64 + i * 16 + q * 4;
#pragma unroll
        for (int j = 0; j < 4; ++j) {
            int col = (hq + wc) * 64 + j * 16 + l15;
#pragma unroll
            for (int r = 0; r < 4; ++r)
                Yb[(bL + l + r) * (size_t)DIN + col] = f2bf(acc[i][j][r]);
        }
    }
}

// ---------------- layernorm * silu(z), in place on Yb (bf16x8 vectorized) ----------------
__global__ __launch_bounds__(256) void k_norm(u16* Yb, const u16* Zb, const void* nw, const int* flagp) {
    int fl = *flagp;
    size_t row = blockIdx.x;
    int t = threadIdx.x;
    size_t base = row * (size_t)DIN + (size_t)t * 8;
    bf16x8 yv = *(const bf16x8*)(Yb + base);
    float v[8];
#pragma unroll
    for (int k = 0; k < 8; ++k) v[k] = bf2f((u16)yv[k]);
    float s = 0.f;
#pragma unroll
    for (int k = 0; k < 8; ++k) s += v[k];
#pragma unroll
    for (int off = 32; off > 0; off >>= 1) s += __shfl_down(s, off);
    __shared__ float red[4];
    int wid = t >> 6, lid = t & 63;
    if (lid == 0) red[wid] = s;
    __syncthreads();
    float mu = (red[0] + red[1] + red[2] + red[3]) * (1.f / 2048.f);
    float d = 0.f;
#pragma unroll
    for (int k = 0; k < 8; ++k) { float e = v[k] - mu; d += e * e; }
#pragma unroll
    for (int off = 32; off > 0; off >>= 1) d += __shfl_down(d, off);
    __syncthreads();
    if (lid == 0) red[wid] = d;
    __syncthreads();
    float var = (red[0] + red[1] + red[2] + red[3]) * (1.f / 2048.f);
    float rs = rsqrtf(var + 1e-5f);
    bf16x8 zv = *(const bf16x8*)(Zb + base);
    bf16x8 ov;
#pragma unroll
    for (int k = 0; k < 8; ++k) {
        float z = bf2f((u16)zv[k]);
        float sz = z / (1.f + __expf(-z));
        ov[k] = (short)f2bf((v[k] - mu) * rs * ldin(nw, (size_t)t * 8 + k, fl) * sz);
    }
    *(bf16x8*)(Yb + base) = ov;
}

extern "C" void kernel_launch(void* const* d_in, const int* in_sizes, int n_in,
                              void* d_out, int out_size, void* d_ws, size_t ws_size,
                              hipStream_t stream) {
    const void* u    = d_in[0];
    const void* Win  = d_in[1];
    const void* cw   = d_in[2];
    const void* cb   = d_in[3];
    const void* dtb  = d_in[4];
    const void* alog = d_in[5];
    const void* nw   = d_in[6];
    const void* Wout = d_in[7];

    char* base = (char*)d_ws;
    int*  flag  = (int*)base;
    u16*  Zb    = (u16*)(base + 256);
    u16*  XBCr  = (u16*)(base + 33554688);
    u16*  XCb   = (u16*)(base + 71303424);
    u16*  ST    = (u16*)(base + 109052160);
    u16*  G     = (u16*)(base + 125829376);
    float* DTc  = (float*)(base + 130023680);
    float* ACS  = (float*)(base + 131072256);
    float* AL   = (float*)(base + 132120832);
    u16*  DTraw = (u16*)(base + 132124928);
    u16*  Yb    = XBCr;
    u16*  Ub    = (u16*)(base + 71303424);
    u16*  WinT  = (u16*)(base + 88080640);
    u16*  WoutT = (u16*)(base + 109052160);

    k_detect<<<1, 256, 0, stream>>>(u, flag);
    k_cast<<<8192, 256, 0, stream>>>(u, Ub, flag, 2097152);
    // WinT padded to 4608 rows (zero-filled) so the 256-wide N tiling is exact
    k_transpose<<<dim3(144, 32), 256, 0, stream>>>(Win, WinT, 1024, 4384, flag);
    k_gemm8<<<dim3(576), 512, 0, stream>>>(Ub, WinT, Zb, XBCr, DTraw);
    k_dtcum<<<1024, 256, 0, stream>>>(DTraw, dtb, alog, flag, DTc, ACS, AL);
    k_conv<<<dim3(9, 8192), 256, 0, stream>>>(XBCr, cw, cb, flag, XCb);
    k_scores<<<dim3(2, 2, 32), 256, 0, stream>>>(XCb, G);
    k_states<<<1024, 256, 0, stream>>>(XCb, DTc, ACS, AL, ST);
    k_scan<<<256, 256, 0, stream>>>(AL, ST);
    k_yfused<<<dim3(16, 2, 32), 256, 0, stream>>>(XCb, DTc, ACS, G, ST, Yb);
    k_transpose<<<dim3(32, 64), 256, 0, stream>>>(Wout, WoutT, 2048, 1024, flag);
    k_norm<<<8192, 256, 0, stream>>>(Yb, Zb, nw, flag);
    k_gemm8o<<<dim3(256), 512, 0, stream>>>(Yb, WoutT, d_out, flag);
}